// Round 10
// baseline (524.234 us; speedup 1.0000x reference)
//
// GAT fused pipeline v3.1 — diagnostic: att1 4-way node-range split (surfaces
// gemm1-v3 counters / residual kernels in top-5). gemm1 v3 frozen.
#include <hip/hip_runtime.h>
#include <math.h>

#define N_NODES 50000
#define N_EDGES 800000
#define NFEAT 512
#define NHID 64
#define NHEAD 8
#define NCLASS 40
#define NEG_SLOPE 0.2f

#define N_RT 3125           // 50000/16 row tiles
#define N_RT_PAD 3128       // padded to multiple of 8
#define SCAN_NBLK 49        // ceil(50000/1024)
#define RT_BLK 4            // rowtiles per gemm1 block (64 rows)
#define ATT1_CHUNK 12500    // nodes per att1 dispatch (4 dispatches)

typedef __attribute__((ext_vector_type(8))) short short8;
typedef __attribute__((ext_vector_type(4))) short short4v;
typedef __attribute__((ext_vector_type(4))) float f32x4;

__device__ __forceinline__ float bf2f(short s) {
    return __uint_as_float(((unsigned)(unsigned short)s) << 16);
}
__device__ __forceinline__ short f2bf(float f) {
    unsigned u = __float_as_uint(f);
    unsigned r = (u + 0x7FFFu + ((u >> 16) & 1u)) >> 16;
    return (short)(unsigned short)r;
}
// LDS 16B-slot swizzle: staging writes 32-way -> conflict-free (verified r7:
// SQ_LDS_BANK_CONFLICT 2.8M -> 0); reads stay conflict-free; bijective.
__device__ __forceinline__ int swz(int s) { return s ^ ((s >> 4) & 7); }

// h1 row permutation: slot c' = head*64 + f'; orig feature: forig = ((f'&3)<<4)|(f'>>2).
// Wp1a layout (augmented): ((g*16+ks)*9 + ct)*64*8 shorts; ct=8 holds score
// columns [ss_h(2g), sd_h(2g), ss_h(2g+1), sd_h(2g+1), 0...] built from Wa = W1@a1.

// ---------------- CSR build ----------------

__global__ void count_deg(const int* __restrict__ el, int* __restrict__ deg) {
    int e = blockIdx.x * blockDim.x + threadIdx.x;
    if (e < N_EDGES) atomicAdd(&deg[el[N_EDGES + e]], 1);
}

__global__ __launch_bounds__(256) void scan1(const int* __restrict__ deg,
                                             int* __restrict__ loc,
                                             int* __restrict__ bsum) {
    int tid = threadIdx.x, lane = tid & 63, w = tid >> 6;
    int base = blockIdx.x * 1024 + tid * 4;
    int d0 = (base + 0 < N_NODES) ? deg[base + 0] : 0;
    int d1 = (base + 1 < N_NODES) ? deg[base + 1] : 0;
    int d2 = (base + 2 < N_NODES) ? deg[base + 2] : 0;
    int d3 = (base + 3 < N_NODES) ? deg[base + 3] : 0;
    int s0 = d0, s1 = s0 + d1, s2 = s1 + d2, s3 = s2 + d3;
    int t = s3;
#pragma unroll
    for (int d = 1; d < 64; d <<= 1) {
        int u = __shfl_up(t, d);
        if (lane >= d) t += u;
    }
    __shared__ int wsum[4];
    if (lane == 63) wsum[w] = t;
    __syncthreads();
    int woff = 0;
#pragma unroll
    for (int j = 0; j < 4; ++j) woff += (j < w) ? wsum[j] : 0;
    int excl = woff + t - s3;
    if (base + 0 < N_NODES) loc[base + 0] = excl + s0;
    if (base + 1 < N_NODES) loc[base + 1] = excl + s1;
    if (base + 2 < N_NODES) loc[base + 2] = excl + s2;
    if (base + 3 < N_NODES) loc[base + 3] = excl + s3;
    if (tid == 255) bsum[blockIdx.x] = woff + t;
}

// scan3 with scan2 folded in: each block reduces bsum[0..bid) itself
__global__ __launch_bounds__(256) void scan3(const int* __restrict__ deg,
                                             const int* __restrict__ loc,
                                             const int* __restrict__ bsum,
                                             int* __restrict__ ptr,
                                             int* __restrict__ cursor) {
    __shared__ int sOff;
    if (threadIdx.x < 64) {
        int lane = threadIdx.x;
        int v = (lane < SCAN_NBLK && lane < (int)blockIdx.x) ? bsum[lane] : 0;
#pragma unroll
        for (int m = 1; m < 64; m <<= 1) v += __shfl_xor(v, m);
        if (lane == 0) sOff = v;
    }
    __syncthreads();
    int off = sOff;
    int base = blockIdx.x * 1024 + threadIdx.x * 4;
    if (blockIdx.x == 0 && threadIdx.x == 0) ptr[0] = 0;
#pragma unroll
    for (int k = 0; k < 4; ++k) {
        int i = base + k;
        if (i < N_NODES) {
            int P = off + loc[i];
            ptr[i + 1] = P;
            cursor[i] = P - deg[i];
        }
    }
}

__global__ void scatter_k(const int* __restrict__ el, int* __restrict__ cursor,
                          int* __restrict__ esrc) {
    int e = blockIdx.x * blockDim.x + threadIdx.x;
    if (e >= N_EDGES) return;
    int dst = el[N_EDGES + e];
    int p = atomicAdd(&cursor[dst], 1);
    esrc[p] = el[e];
}

// ---------------- pack W1(+scores), W2 into MFMA B-fragment layout (bf16) ----------------
__global__ __launch_bounds__(256) void pack_w(const float* __restrict__ W1,
                                              const float* __restrict__ W2,
                                              const float* __restrict__ a1,
                                              short* __restrict__ Wp1a,
                                              short* __restrict__ Wp2) {
    int t = blockIdx.x * 256 + threadIdx.x;
    if (t < 36864) {                    // 4g x 16ks x 9ct x 64l
        int l = t & 63;
        int idx = t >> 6;               // 0..575
        int ct = idx % 9;
        int ksg = idx / 9;              // g*16+ks
        int ks = ksg & 15, g = ksg >> 4;
        short8 o;
        if (ct < 8) {
            int c = g * 128 + ct * 16 + (l & 15);
            int head = c >> 6, f = c & 63;
            int k0 = ks * 32 + (l >> 4) * 8;
#pragma unroll
            for (int j = 0; j < 8; ++j)
                o[j] = f2bf(W1[(size_t)head * NFEAT * NHID + (k0 + j) * NHID + f]);
        } else {
            // score columns: col 0..3 = [ss(2g), sd(2g), ss(2g+1), sd(2g+1)]
            int col = l & 15;
            int k0 = ks * 32 + (l >> 4) * 8;
#pragma unroll
            for (int j = 0; j < 8; ++j) o[j] = 0;
            if (col < 4) {
                int head = 2 * g + (col >> 1);
                const float* av = a1 + head * 128 + (col & 1) * 64;
                const float* wb = W1 + (size_t)head * NFEAT * NHID;
#pragma unroll
                for (int j = 0; j < 8; ++j) {
                    const float* wr = wb + (size_t)(k0 + j) * NHID;
                    float s = 0.f;
                    for (int f = 0; f < NHID; ++f) s += wr[f] * av[f];
                    o[j] = f2bf(s);
                }
            }
        }
        *(short8*)(Wp1a + (size_t)t * 8) = o;
    } else if (t < 36864 + 3072) {
        int u = t - 36864;
        int l = u & 63;
        int kc = u >> 6;                 // ks*3+ct
        int ct2 = kc % 3, ks = kc / 3;
        int col = ct2 * 16 + (l & 15);
        short8 o;
#pragma unroll
        for (int j = 0; j < 8; ++j) {
            int kp = ks * 32 + (l >> 4) * 8 + j;      // permuted K slot (= c')
            int head = kp >> 6, fp = kp & 63;
            int l15 = fp >> 2, ctp = fp & 3;
            int ct = ((head & 1) << 2) | ctp;
            int gg = head >> 1;
            int orig_k = gg * 128 + ct * 16 + l15;
            o[j] = (col < NCLASS) ? f2bf(W2[(size_t)orig_k * NCLASS + col]) : (short)0;
        }
        *(short8*)(Wp2 + (size_t)u * 8) = o;
    }
}

// ---------------- gemm1 v3: 4 rowtiles/block, scores as 9th B-tile, no shfl epilogue ----
__global__ __launch_bounds__(256, 2) void gemm1(const float* __restrict__ x,
                                                const short* __restrict__ Wp1a,
                                                short* __restrict__ h1p,
                                                float* __restrict__ s1s,
                                                float* __restrict__ s1d) {
    __shared__ short As[RT_BLK * 16 * 64 * 8];     // 64 KB
    int w = threadIdx.x >> 6, l = threadIdx.x & 63;
    int g = w;                                 // wave = colgroup
    int rt0 = blockIdx.x * RT_BLK;
    int row0 = rt0 * 16;

    // stage 64 rows x 512 cols of x into LDS A-frag layout (swizzled slots)
#pragma unroll
    for (int u = 0; u < 4 * RT_BLK; ++u) {
        int idx = threadIdx.x + u * 256;       // 0..4095
        int rl = idx >> 6, cg = idx & 63;      // row-local (0..63), col-group
        int row = row0 + rl;
        short8 o;
        if (row < N_NODES) {
            const float* p = x + (size_t)row * NFEAT + cg * 8;
            f32x4 v0 = __builtin_nontemporal_load((const f32x4*)p);
            f32x4 v1 = __builtin_nontemporal_load((const f32x4*)(p + 4));
            o[0] = f2bf(v0[0]); o[1] = f2bf(v0[1]); o[2] = f2bf(v0[2]); o[3] = f2bf(v0[3]);
            o[4] = f2bf(v1[0]); o[5] = f2bf(v1[1]); o[6] = f2bf(v1[2]); o[7] = f2bf(v1[3]);
        } else {
#pragma unroll
            for (int j = 0; j < 8; ++j) o[j] = 0;
        }
        int rtl = rl >> 4, rloc = rl & 15, ks = cg >> 2, sub = cg & 3;
        int slot = (rtl * 16 + ks) * 64 + rloc + sub * 16;
        *(short8*)(As + swz(slot) * 8) = o;
    }
    __syncthreads();

    f32x4 acc[RT_BLK][9];
#pragma unroll
    for (int i = 0; i < RT_BLK; ++i)
#pragma unroll
        for (int ct = 0; ct < 9; ++ct) acc[i][ct] = (f32x4){0.f, 0.f, 0.f, 0.f};

    const short* bP = Wp1a + (size_t)g * (16 * 9 * 512) + l * 8;   // ks stride 4608
#pragma unroll 2
    for (int ks = 0; ks < 16; ++ks) {
        short8 b[9];
#pragma unroll
        for (int ct = 0; ct < 9; ++ct) b[ct] = *(const short8*)(bP + ks * 4608 + ct * 512);
        short8 a[RT_BLK];
#pragma unroll
        for (int i = 0; i < RT_BLK; ++i)
            a[i] = *(const short8*)(As + swz((i * 16 + ks) * 64 + l) * 8);
#pragma unroll
        for (int i = 0; i < RT_BLK; ++i)
#pragma unroll
            for (int ct = 0; ct < 9; ++ct)
                acc[i][ct] = __builtin_amdgcn_mfma_f32_16x16x32_bf16(a[i], b[ct], acc[i][ct], 0, 0, 0);
    }

    int l15 = l & 15;
    int rbase = (l >> 4) * 4;
#pragma unroll
    for (int i = 0; i < RT_BLK; ++i)
#pragma unroll
        for (int r = 0; r < 4; ++r) {
            int row = (rt0 + i) * 16 + rbase + r;
            if (row < N_NODES) {
                short4v o0, o1;
#pragma unroll
                for (int c = 0; c < 4; ++c) { o0[c] = f2bf(acc[i][c][r]); o1[c] = f2bf(acc[i][4 + c][r]); }
                size_t base = (size_t)row * 512 + g * 128 + l15 * 4;
                *(short4v*)(h1p + base) = o0;
                *(short4v*)(h1p + base + 64) = o1;
                float sv = acc[i][8][r];
                if (l15 == 0)      s1s[row * 8 + 2 * g]     = sv;
                else if (l15 == 1) s1d[row * 8 + 2 * g]     = sv;
                else if (l15 == 2) s1s[row * 8 + 2 * g + 1] = sv;
                else if (l15 == 3) s1d[row * 8 + 2 * g + 1] = sv;
            }
        }
}

// ---------------- fused layer-1 attention: wave per dst, ALL heads ----------------
// Node-range chunked (4 dispatches) for profiler visibility; pipelined 4-wide gather.
__global__ __launch_bounds__(256, 4) void att1(const int* __restrict__ ptr,
                                               const int* __restrict__ esrc,
                                               const float* __restrict__ s1s,
                                               const float* __restrict__ s1d,
                                               const short* __restrict__ h1p,
                                               const float* __restrict__ b1,
                                               short* __restrict__ hcat,
                                               int n0) {
    int n = n0 + blockIdx.x * 4 + (threadIdx.x >> 6);
    int l = threadIdx.x & 63;
    if (n >= N_NODES) return;
    int beg = ptr[n], end = ptr[n + 1];
    int h = l >> 3;
    float sd = s1d[n * 8 + h];
    float den = 0.f;
    float acc[8] = {0.f, 0.f, 0.f, 0.f, 0.f, 0.f, 0.f, 0.f};
    const short* hb = h1p + l * 8;
    if (beg < end) {
        int last = end - 1;
        int p1 = (beg + 1 <= last) ? beg + 1 : last;
        int p2 = (beg + 2 <= last) ? beg + 2 : last;
        int p3 = (beg + 3 <= last) ? beg + 3 : last;
        int s0 = esrc[beg], s1 = esrc[p1], s2 = esrc[p2], s3 = esrc[p3];
        short8 v0 = *(const short8*)(hb + (size_t)s0 * 512);
        short8 v1 = *(const short8*)(hb + (size_t)s1 * 512);
        short8 v2 = *(const short8*)(hb + (size_t)s2 * 512);
        short8 v3 = *(const short8*)(hb + (size_t)s3 * 512);
        float ss0 = s1s[s0 * 8 + h], ss1 = s1s[s1 * 8 + h];
        float ss2 = s1s[s2 * 8 + h], ss3 = s1s[s3 * 8 + h];
        for (int i = beg; i < end; i += 4) {
            int ni = i + 4;
            int t0 = s0, t1 = s1, t2 = s2, t3 = s3;
            short8 u0 = v0, u1 = v1, u2 = v2, u3 = v3;
            float ts0 = ss0, ts1 = ss1, ts2 = ss2, ts3 = ss3;
            if (ni < end) {                       // wave-uniform branch
                int q1 = (ni + 1 <= last) ? ni + 1 : last;
                int q2 = (ni + 2 <= last) ? ni + 2 : last;
                int q3 = (ni + 3 <= last) ? ni + 3 : last;
                t0 = esrc[ni]; t1 = esrc[q1]; t2 = esrc[q2]; t3 = esrc[q3];
                u0 = *(const short8*)(hb + (size_t)t0 * 512);
                u1 = *(const short8*)(hb + (size_t)t1 * 512);
                u2 = *(const short8*)(hb + (size_t)t2 * 512);
                u3 = *(const short8*)(hb + (size_t)t3 * 512);
                ts0 = s1s[t0 * 8 + h]; ts1 = s1s[t1 * 8 + h];
                ts2 = s1s[t2 * 8 + h]; ts3 = s1s[t3 * 8 + h];
            }
            float e0 = ss0 + sd, e1 = ss1 + sd, e2 = ss2 + sd, e3 = ss3 + sd;
            e0 = fmaxf(e0, NEG_SLOPE * e0);
            e1 = fmaxf(e1, NEG_SLOPE * e1);
            e2 = fmaxf(e2, NEG_SLOPE * e2);
            e3 = fmaxf(e3, NEG_SLOPE * e3);
            float w0 = __expf(e0);
            float w1 = (i + 1 < end) ? __expf(e1) : 0.f;
            float w2 = (i + 2 < end) ? __expf(e2) : 0.f;
            float w3 = (i + 3 < end) ? __expf(e3) : 0.f;
            den += (w0 + w1) + (w2 + w3);
#pragma unroll
            for (int j = 0; j < 8; ++j)
                acc[j] += (w0 * bf2f(v0[j]) + w1 * bf2f(v1[j])) +
                          (w2 * bf2f(v2[j]) + w3 * bf2f(v3[j]));
            s0 = t0; s1 = t1; s2 = t2; s3 = t3;
            v0 = u0; v1 = u1; v2 = u2; v3 = u3;
            ss0 = ts0; ss1 = ts1; ss2 = ts2; ss3 = ts3;
        }
    }
    float rden = 1.f / fmaxf(den, 1e-16f);
    short8 o;
#pragma unroll
    for (int j = 0; j < 8; ++j) {
        // permuted slot c' = l*8+j  ->  orig b1 index = head*64 + (j&3)*16 + (l&7)*2 + (j>>2)
        int forig = (j & 3) * 16 + (l & 7) * 2 + (j >> 2);
        float v = acc[j] * rden + b1[h * 64 + forig];
        v = v > 0.f ? v : (__expf(v) - 1.f);    // ELU
        o[j] = f2bf(v);
    }
    *(short8*)(hcat + (size_t)n * 512 + l * 8) = o;
}

// ---------------- gemm2: row-major hcat A-frags + fused s2 scores ----------------
__global__ __launch_bounds__(256) void gemm2(const short* __restrict__ hcat,
                                             const short* __restrict__ Wp2,
                                             const float* __restrict__ a2,
                                             short* __restrict__ h2,
                                             float* __restrict__ s2s,
                                             float* __restrict__ s2d) {
    int w = threadIdx.x >> 6, l = threadIdx.x & 63;
    int rt = blockIdx.x * 4 + w;                  // < N_RT_PAD
    int arow = rt * 16 + (l & 15);
    const short* aBase = hcat + (size_t)arow * 512 + (l >> 4) * 8;
    f32x4 acc[3];
#pragma unroll
    for (int ct = 0; ct < 3; ++ct) acc[ct] = (f32x4){0.f, 0.f, 0.f, 0.f};
#pragma unroll 2
    for (int ks = 0; ks < 16; ++ks) {
        short8 a = *(const short8*)(aBase + ks * 32);
        const short* bp = Wp2 + (size_t)(ks * 3) * 512 + l * 8;
#pragma unroll
        for (int ct = 0; ct < 3; ++ct) {
            short8 b = *(const short8*)(bp + ct * 512);
            acc[ct] = __builtin_amdgcn_mfma_f32_16x16x32_bf16(a, b, acc[ct], 0, 0, 0);
        }
    }
    float ps[4] = {0.f, 0.f, 0.f, 0.f}, pd[4] = {0.f, 0.f, 0.f, 0.f};
    int cl = l & 15, rb = (l >> 4) * 4;
#pragma unroll
    for (int ct = 0; ct < 3; ++ct) {
        int col = ct * 16 + cl;
        if (col < NCLASS) {
#pragma unroll
            for (int r = 0; r < 4; ++r) {
                ps[r] += acc[ct][r] * a2[col];
                pd[r] += acc[ct][r] * a2[NCLASS + col];
                int row = rt * 16 + rb + r;
                if (row < N_NODES) h2[(size_t)row * NCLASS + col] = f2bf(acc[ct][r]);
            }
        }
    }
#pragma unroll
    for (int mask = 1; mask < 16; mask <<= 1)
#pragma unroll
        for (int r = 0; r < 4; ++r) {
            ps[r] += __shfl_xor(ps[r], mask);
            pd[r] += __shfl_xor(pd[r], mask);
        }
    if (cl == 0) {
#pragma unroll
        for (int r = 0; r < 4; ++r) {
            int row = rt * 16 + rb + r;
            if (row < N_NODES) { s2s[row] = ps[r]; s2d[row] = pd[r]; }
        }
    }
}

// ---------------- fused layer-2 attention + log_softmax: wave per dst, 4-wide unroll ----------------
__global__ __launch_bounds__(256, 4) void att2(const int* __restrict__ ptr,
                                               const int* __restrict__ esrc,
                                               const float* __restrict__ s2s,
                                               const float* __restrict__ s2d,
                                               const short* __restrict__ h2,
                                               const float* __restrict__ b2,
                                               float* __restrict__ out) {
    int n = blockIdx.x * 4 + (threadIdx.x >> 6);
    int l = threadIdx.x & 63;
    if (n >= N_NODES) return;
    int beg = ptr[n], end = ptr[n + 1];
    float sd = s2d[n];
    float den = 0.f, acc = 0.f;
    int last = end - 1;
    bool act = (l < NCLASS);
    for (int i = beg; i < end; i += 4) {
        int i1 = (i + 1 <= last) ? i + 1 : last;
        int i2 = (i + 2 <= last) ? i + 2 : last;
        int i3 = (i + 3 <= last) ? i + 3 : last;
        int s0 = esrc[i], s1 = esrc[i1], s2 = esrc[i2], s3 = esrc[i3];
        float h0 = act ? bf2f(h2[(size_t)s0 * NCLASS + l]) : 0.f;
        float h1 = act ? bf2f(h2[(size_t)s1 * NCLASS + l]) : 0.f;
        float hh2 = act ? bf2f(h2[(size_t)s2 * NCLASS + l]) : 0.f;
        float h3 = act ? bf2f(h2[(size_t)s3 * NCLASS + l]) : 0.f;
        float e0 = s2s[s0] + sd;
        float e1 = s2s[s1] + sd;
        float e2 = s2s[s2] + sd;
        float e3 = s2s[s3] + sd;
        e0 = fmaxf(e0, NEG_SLOPE * e0);
        e1 = fmaxf(e1, NEG_SLOPE * e1);
        e2 = fmaxf(e2, NEG_SLOPE * e2);
        e3 = fmaxf(e3, NEG_SLOPE * e3);
        float w0 = __expf(e0);
        float w1 = (i + 1 < end) ? __expf(e1) : 0.f;
        float w2 = (i + 2 < end) ? __expf(e2) : 0.f;
        float w3 = (i + 3 < end) ? __expf(e3) : 0.f;
        den += (w0 + w1) + (w2 + w3);
        acc += (w0 * h0 + w1 * h1) + (w2 * hh2 + w3 * h3);
    }
    float v = act ? acc / fmaxf(den, 1e-16f) + b2[l] : -INFINITY;
    float mx = v;
#pragma unroll
    for (int o = 32; o; o >>= 1) mx = fmaxf(mx, __shfl_down(mx, o));
    mx = __shfl(mx, 0);
    float ex = act ? __expf(v - mx) : 0.f;
    float s = ex;
#pragma unroll
    for (int o = 32; o; o >>= 1) s += __shfl_down(s, o);
    s = __shfl(s, 0);
    float ls = __logf(s);
    if (act) out[(size_t)n * NCLASS + l] = v - mx - ls;
}

// ---------------- launch ----------------

extern "C" void kernel_launch(void* const* d_in, const int* in_sizes, int n_in,
                              void* d_out, int out_size, void* d_ws, size_t ws_size,
                              hipStream_t stream) {
    const float* x  = (const float*)d_in[0];
    const int*   el = (const int*)d_in[1];
    const float* W1 = (const float*)d_in[2];
    const float* a1 = (const float*)d_in[3];
    const float* b1 = (const float*)d_in[4];
    const float* W2 = (const float*)d_in[5];
    const float* a2 = (const float*)d_in[6];
    const float* b2 = (const float*)d_in[7];
    float* out = (float*)d_out;

    short* sbase = (short*)d_ws;
    short* Wp1a  = sbase;                          //    294,912 (in formerly-unused region)
    short* hcat  = sbase + 25624576;               // 25,624,576 (row-major, permuted cols)
    short* h1p   = sbase + 51249152;               // 25,600,000
    short* Wp2   = sbase + 77111296;               //     24,576
    short* h2    = sbase + 77135872;               //  2,000,000
    float* fbase = (float*)(sbase + 79135872);
    float* s1s   = fbase;                          //    400,000
    float* s1d   = fbase + 400000;                 //    400,000
    float* s2s   = fbase + 800000;                 //     50,000
    float* s2d   = fbase + 850000;                 //     50,000
    int*   ibase = (int*)(fbase + 900000);
    int*   deg    = ibase;                         //     50,000
    int*   ptr    = ibase + 50000;                 //     50,001
    int*   cursor = ibase + 100001;                //     50,000
    int*   esrc   = ibase + 150001;                //    800,000
    int*   loc    = ibase + 950001;                //     50,000
    int*   bsum   = ibase + 1000001;               //         64

    // ---- CSR build ----
    hipMemsetAsync(deg, 0, (size_t)N_NODES * 4, stream);
    count_deg<<<(N_EDGES + 255) / 256, 256, 0, stream>>>(el, deg);
    scan1<<<SCAN_NBLK, 256, 0, stream>>>(deg, loc, bsum);
    scan3<<<SCAN_NBLK, 256, 0, stream>>>(deg, loc, bsum, ptr, cursor);
    scatter_k<<<(N_EDGES + 255) / 256, 256, 0, stream>>>(el, cursor, esrc);

    // ---- weight packing (Wa score columns folded into Wp1a) ----
    pack_w<<<156, 256, 0, stream>>>(W1, W2, a1, Wp1a, Wp2);

    // ---- layer 1 ----
    gemm1<<<N_RT_PAD / RT_BLK, 256, 0, stream>>>(x, Wp1a, h1p, s1s, s1d);
    att1<<<ATT1_CHUNK / 4, 256, 0, stream>>>(ptr, esrc, s1s, s1d, h1p, b1, hcat, 0);
    att1<<<ATT1_CHUNK / 4, 256, 0, stream>>>(ptr, esrc, s1s, s1d, h1p, b1, hcat, 12500);
    att1<<<ATT1_CHUNK / 4, 256, 0, stream>>>(ptr, esrc, s1s, s1d, h1p, b1, hcat, 25000);
    att1<<<ATT1_CHUNK / 4, 256, 0, stream>>>(ptr, esrc, s1s, s1d, h1p, b1, hcat, 37500);

    // ---- layer 2 ----
    gemm2<<<N_RT_PAD / 4, 256, 0, stream>>>(hcat, Wp2, a2, h2, s2s, s2d);
    att2<<<(N_NODES + 3) / 4, 256, 0, stream>>>(ptr, esrc, s2s, s2d, h2, b2, out);
}

// Round 11
// 515.023 us; speedup vs baseline: 1.0179x; 1.0179x over previous
//
// GAT fused pipeline v3.2 — att2: software-pipelined 4-wide gather (8 edges in
// flight; att2 is latency-bound at 6% HBM, unlike att1). att1 split 2-way
// (diagnostics at ~half the cost). gemm1 v3 frozen.
#include <hip/hip_runtime.h>
#include <math.h>

#define N_NODES 50000
#define N_EDGES 800000
#define NFEAT 512
#define NHID 64
#define NHEAD 8
#define NCLASS 40
#define NEG_SLOPE 0.2f

#define N_RT 3125           // 50000/16 row tiles
#define N_RT_PAD 3128       // padded to multiple of 8
#define SCAN_NBLK 49        // ceil(50000/1024)
#define RT_BLK 4            // rowtiles per gemm1 block (64 rows)
#define ATT1_CHUNK 25000    // nodes per att1 dispatch (2 dispatches)

typedef __attribute__((ext_vector_type(8))) short short8;
typedef __attribute__((ext_vector_type(4))) short short4v;
typedef __attribute__((ext_vector_type(4))) float f32x4;

__device__ __forceinline__ float bf2f(short s) {
    return __uint_as_float(((unsigned)(unsigned short)s) << 16);
}
__device__ __forceinline__ short f2bf(float f) {
    unsigned u = __float_as_uint(f);
    unsigned r = (u + 0x7FFFu + ((u >> 16) & 1u)) >> 16;
    return (short)(unsigned short)r;
}
// LDS 16B-slot swizzle: staging writes 32-way -> conflict-free (verified r7:
// SQ_LDS_BANK_CONFLICT 2.8M -> 0); reads stay conflict-free; bijective.
__device__ __forceinline__ int swz(int s) { return s ^ ((s >> 4) & 7); }

// h1 row permutation: slot c' = head*64 + f'; orig feature: forig = ((f'&3)<<4)|(f'>>2).
// Wp1a layout (augmented): ((g*16+ks)*9 + ct)*64*8 shorts; ct=8 holds score
// columns [ss_h(2g), sd_h(2g), ss_h(2g+1), sd_h(2g+1), 0...] built from Wa = W1@a1.

// ---------------- CSR build ----------------

__global__ void count_deg(const int* __restrict__ el, int* __restrict__ deg) {
    int e = blockIdx.x * blockDim.x + threadIdx.x;
    if (e < N_EDGES) atomicAdd(&deg[el[N_EDGES + e]], 1);
}

__global__ __launch_bounds__(256) void scan1(const int* __restrict__ deg,
                                             int* __restrict__ loc,
                                             int* __restrict__ bsum) {
    int tid = threadIdx.x, lane = tid & 63, w = tid >> 6;
    int base = blockIdx.x * 1024 + tid * 4;
    int d0 = (base + 0 < N_NODES) ? deg[base + 0] : 0;
    int d1 = (base + 1 < N_NODES) ? deg[base + 1] : 0;
    int d2 = (base + 2 < N_NODES) ? deg[base + 2] : 0;
    int d3 = (base + 3 < N_NODES) ? deg[base + 3] : 0;
    int s0 = d0, s1 = s0 + d1, s2 = s1 + d2, s3 = s2 + d3;
    int t = s3;
#pragma unroll
    for (int d = 1; d < 64; d <<= 1) {
        int u = __shfl_up(t, d);
        if (lane >= d) t += u;
    }
    __shared__ int wsum[4];
    if (lane == 63) wsum[w] = t;
    __syncthreads();
    int woff = 0;
#pragma unroll
    for (int j = 0; j < 4; ++j) woff += (j < w) ? wsum[j] : 0;
    int excl = woff + t - s3;
    if (base + 0 < N_NODES) loc[base + 0] = excl + s0;
    if (base + 1 < N_NODES) loc[base + 1] = excl + s1;
    if (base + 2 < N_NODES) loc[base + 2] = excl + s2;
    if (base + 3 < N_NODES) loc[base + 3] = excl + s3;
    if (tid == 255) bsum[blockIdx.x] = woff + t;
}

// scan3 with scan2 folded in: each block reduces bsum[0..bid) itself
__global__ __launch_bounds__(256) void scan3(const int* __restrict__ deg,
                                             const int* __restrict__ loc,
                                             const int* __restrict__ bsum,
                                             int* __restrict__ ptr,
                                             int* __restrict__ cursor) {
    __shared__ int sOff;
    if (threadIdx.x < 64) {
        int lane = threadIdx.x;
        int v = (lane < SCAN_NBLK && lane < (int)blockIdx.x) ? bsum[lane] : 0;
#pragma unroll
        for (int m = 1; m < 64; m <<= 1) v += __shfl_xor(v, m);
        if (lane == 0) sOff = v;
    }
    __syncthreads();
    int off = sOff;
    int base = blockIdx.x * 1024 + threadIdx.x * 4;
    if (blockIdx.x == 0 && threadIdx.x == 0) ptr[0] = 0;
#pragma unroll
    for (int k = 0; k < 4; ++k) {
        int i = base + k;
        if (i < N_NODES) {
            int P = off + loc[i];
            ptr[i + 1] = P;
            cursor[i] = P - deg[i];
        }
    }
}

__global__ void scatter_k(const int* __restrict__ el, int* __restrict__ cursor,
                          int* __restrict__ esrc) {
    int e = blockIdx.x * blockDim.x + threadIdx.x;
    if (e >= N_EDGES) return;
    int dst = el[N_EDGES + e];
    int p = atomicAdd(&cursor[dst], 1);
    esrc[p] = el[e];
}

// ---------------- pack W1(+scores), W2 into MFMA B-fragment layout (bf16) ----------------
__global__ __launch_bounds__(256) void pack_w(const float* __restrict__ W1,
                                              const float* __restrict__ W2,
                                              const float* __restrict__ a1,
                                              short* __restrict__ Wp1a,
                                              short* __restrict__ Wp2) {
    int t = blockIdx.x * 256 + threadIdx.x;
    if (t < 36864) {                    // 4g x 16ks x 9ct x 64l
        int l = t & 63;
        int idx = t >> 6;               // 0..575
        int ct = idx % 9;
        int ksg = idx / 9;              // g*16+ks
        int ks = ksg & 15, g = ksg >> 4;
        short8 o;
        if (ct < 8) {
            int c = g * 128 + ct * 16 + (l & 15);
            int head = c >> 6, f = c & 63;
            int k0 = ks * 32 + (l >> 4) * 8;
#pragma unroll
            for (int j = 0; j < 8; ++j)
                o[j] = f2bf(W1[(size_t)head * NFEAT * NHID + (k0 + j) * NHID + f]);
        } else {
            // score columns: col 0..3 = [ss(2g), sd(2g), ss(2g+1), sd(2g+1)]
            int col = l & 15;
            int k0 = ks * 32 + (l >> 4) * 8;
#pragma unroll
            for (int j = 0; j < 8; ++j) o[j] = 0;
            if (col < 4) {
                int head = 2 * g + (col >> 1);
                const float* av = a1 + head * 128 + (col & 1) * 64;
                const float* wb = W1 + (size_t)head * NFEAT * NHID;
#pragma unroll
                for (int j = 0; j < 8; ++j) {
                    const float* wr = wb + (size_t)(k0 + j) * NHID;
                    float s = 0.f;
                    for (int f = 0; f < NHID; ++f) s += wr[f] * av[f];
                    o[j] = f2bf(s);
                }
            }
        }
        *(short8*)(Wp1a + (size_t)t * 8) = o;
    } else if (t < 36864 + 3072) {
        int u = t - 36864;
        int l = u & 63;
        int kc = u >> 6;                 // ks*3+ct
        int ct2 = kc % 3, ks = kc / 3;
        int col = ct2 * 16 + (l & 15);
        short8 o;
#pragma unroll
        for (int j = 0; j < 8; ++j) {
            int kp = ks * 32 + (l >> 4) * 8 + j;      // permuted K slot (= c')
            int head = kp >> 6, fp = kp & 63;
            int l15 = fp >> 2, ctp = fp & 3;
            int ct = ((head & 1) << 2) | ctp;
            int gg = head >> 1;
            int orig_k = gg * 128 + ct * 16 + l15;
            o[j] = (col < NCLASS) ? f2bf(W2[(size_t)orig_k * NCLASS + col]) : (short)0;
        }
        *(short8*)(Wp2 + (size_t)u * 8) = o;
    }
}

// ---------------- gemm1 v3: 4 rowtiles/block, scores as 9th B-tile, no shfl epilogue ----
__global__ __launch_bounds__(256, 2) void gemm1(const float* __restrict__ x,
                                                const short* __restrict__ Wp1a,
                                                short* __restrict__ h1p,
                                                float* __restrict__ s1s,
                                                float* __restrict__ s1d) {
    __shared__ short As[RT_BLK * 16 * 64 * 8];     // 64 KB
    int w = threadIdx.x >> 6, l = threadIdx.x & 63;
    int g = w;                                 // wave = colgroup
    int rt0 = blockIdx.x * RT_BLK;
    int row0 = rt0 * 16;

    // stage 64 rows x 512 cols of x into LDS A-frag layout (swizzled slots)
#pragma unroll
    for (int u = 0; u < 4 * RT_BLK; ++u) {
        int idx = threadIdx.x + u * 256;       // 0..4095
        int rl = idx >> 6, cg = idx & 63;      // row-local (0..63), col-group
        int row = row0 + rl;
        short8 o;
        if (row < N_NODES) {
            const float* p = x + (size_t)row * NFEAT + cg * 8;
            f32x4 v0 = __builtin_nontemporal_load((const f32x4*)p);
            f32x4 v1 = __builtin_nontemporal_load((const f32x4*)(p + 4));
            o[0] = f2bf(v0[0]); o[1] = f2bf(v0[1]); o[2] = f2bf(v0[2]); o[3] = f2bf(v0[3]);
            o[4] = f2bf(v1[0]); o[5] = f2bf(v1[1]); o[6] = f2bf(v1[2]); o[7] = f2bf(v1[3]);
        } else {
#pragma unroll
            for (int j = 0; j < 8; ++j) o[j] = 0;
        }
        int rtl = rl >> 4, rloc = rl & 15, ks = cg >> 2, sub = cg & 3;
        int slot = (rtl * 16 + ks) * 64 + rloc + sub * 16;
        *(short8*)(As + swz(slot) * 8) = o;
    }
    __syncthreads();

    f32x4 acc[RT_BLK][9];
#pragma unroll
    for (int i = 0; i < RT_BLK; ++i)
#pragma unroll
        for (int ct = 0; ct < 9; ++ct) acc[i][ct] = (f32x4){0.f, 0.f, 0.f, 0.f};

    const short* bP = Wp1a + (size_t)g * (16 * 9 * 512) + l * 8;   // ks stride 4608
#pragma unroll 2
    for (int ks = 0; ks < 16; ++ks) {
        short8 b[9];
#pragma unroll
        for (int ct = 0; ct < 9; ++ct) b[ct] = *(const short8*)(bP + ks * 4608 + ct * 512);
        short8 a[RT_BLK];
#pragma unroll
        for (int i = 0; i < RT_BLK; ++i)
            a[i] = *(const short8*)(As + swz((i * 16 + ks) * 64 + l) * 8);
#pragma unroll
        for (int i = 0; i < RT_BLK; ++i)
#pragma unroll
            for (int ct = 0; ct < 9; ++ct)
                acc[i][ct] = __builtin_amdgcn_mfma_f32_16x16x32_bf16(a[i], b[ct], acc[i][ct], 0, 0, 0);
    }

    int l15 = l & 15;
    int rbase = (l >> 4) * 4;
#pragma unroll
    for (int i = 0; i < RT_BLK; ++i)
#pragma unroll
        for (int r = 0; r < 4; ++r) {
            int row = (rt0 + i) * 16 + rbase + r;
            if (row < N_NODES) {
                short4v o0, o1;
#pragma unroll
                for (int c = 0; c < 4; ++c) { o0[c] = f2bf(acc[i][c][r]); o1[c] = f2bf(acc[i][4 + c][r]); }
                size_t base = (size_t)row * 512 + g * 128 + l15 * 4;
                *(short4v*)(h1p + base) = o0;
                *(short4v*)(h1p + base + 64) = o1;
                float sv = acc[i][8][r];
                if (l15 == 0)      s1s[row * 8 + 2 * g]     = sv;
                else if (l15 == 1) s1d[row * 8 + 2 * g]     = sv;
                else if (l15 == 2) s1s[row * 8 + 2 * g + 1] = sv;
                else if (l15 == 3) s1d[row * 8 + 2 * g + 1] = sv;
            }
        }
}

// ---------------- fused layer-1 attention: wave per dst, ALL heads ----------------
// Node-range chunked (2 dispatches) for profiler visibility; pipelined 4-wide gather.
__global__ __launch_bounds__(256, 4) void att1(const int* __restrict__ ptr,
                                               const int* __restrict__ esrc,
                                               const float* __restrict__ s1s,
                                               const float* __restrict__ s1d,
                                               const short* __restrict__ h1p,
                                               const float* __restrict__ b1,
                                               short* __restrict__ hcat,
                                               int n0) {
    int n = n0 + blockIdx.x * 4 + (threadIdx.x >> 6);
    int l = threadIdx.x & 63;
    if (n >= N_NODES) return;
    int beg = ptr[n], end = ptr[n + 1];
    int h = l >> 3;
    float sd = s1d[n * 8 + h];
    float den = 0.f;
    float acc[8] = {0.f, 0.f, 0.f, 0.f, 0.f, 0.f, 0.f, 0.f};
    const short* hb = h1p + l * 8;
    if (beg < end) {
        int last = end - 1;
        int p1 = (beg + 1 <= last) ? beg + 1 : last;
        int p2 = (beg + 2 <= last) ? beg + 2 : last;
        int p3 = (beg + 3 <= last) ? beg + 3 : last;
        int s0 = esrc[beg], s1 = esrc[p1], s2 = esrc[p2], s3 = esrc[p3];
        short8 v0 = *(const short8*)(hb + (size_t)s0 * 512);
        short8 v1 = *(const short8*)(hb + (size_t)s1 * 512);
        short8 v2 = *(const short8*)(hb + (size_t)s2 * 512);
        short8 v3 = *(const short8*)(hb + (size_t)s3 * 512);
        float ss0 = s1s[s0 * 8 + h], ss1 = s1s[s1 * 8 + h];
        float ss2 = s1s[s2 * 8 + h], ss3 = s1s[s3 * 8 + h];
        for (int i = beg; i < end; i += 4) {
            int ni = i + 4;
            int t0 = s0, t1 = s1, t2 = s2, t3 = s3;
            short8 u0 = v0, u1 = v1, u2 = v2, u3 = v3;
            float ts0 = ss0, ts1 = ss1, ts2 = ss2, ts3 = ss3;
            if (ni < end) {                       // wave-uniform branch
                int q1 = (ni + 1 <= last) ? ni + 1 : last;
                int q2 = (ni + 2 <= last) ? ni + 2 : last;
                int q3 = (ni + 3 <= last) ? ni + 3 : last;
                t0 = esrc[ni]; t1 = esrc[q1]; t2 = esrc[q2]; t3 = esrc[q3];
                u0 = *(const short8*)(hb + (size_t)t0 * 512);
                u1 = *(const short8*)(hb + (size_t)t1 * 512);
                u2 = *(const short8*)(hb + (size_t)t2 * 512);
                u3 = *(const short8*)(hb + (size_t)t3 * 512);
                ts0 = s1s[t0 * 8 + h]; ts1 = s1s[t1 * 8 + h];
                ts2 = s1s[t2 * 8 + h]; ts3 = s1s[t3 * 8 + h];
            }
            float e0 = ss0 + sd, e1 = ss1 + sd, e2 = ss2 + sd, e3 = ss3 + sd;
            e0 = fmaxf(e0, NEG_SLOPE * e0);
            e1 = fmaxf(e1, NEG_SLOPE * e1);
            e2 = fmaxf(e2, NEG_SLOPE * e2);
            e3 = fmaxf(e3, NEG_SLOPE * e3);
            float w0 = __expf(e0);
            float w1 = (i + 1 < end) ? __expf(e1) : 0.f;
            float w2 = (i + 2 < end) ? __expf(e2) : 0.f;
            float w3 = (i + 3 < end) ? __expf(e3) : 0.f;
            den += (w0 + w1) + (w2 + w3);
#pragma unroll
            for (int j = 0; j < 8; ++j)
                acc[j] += (w0 * bf2f(v0[j]) + w1 * bf2f(v1[j])) +
                          (w2 * bf2f(v2[j]) + w3 * bf2f(v3[j]));
            s0 = t0; s1 = t1; s2 = t2; s3 = t3;
            v0 = u0; v1 = u1; v2 = u2; v3 = u3;
            ss0 = ts0; ss1 = ts1; ss2 = ts2; ss3 = ts3;
        }
    }
    float rden = 1.f / fmaxf(den, 1e-16f);
    short8 o;
#pragma unroll
    for (int j = 0; j < 8; ++j) {
        // permuted slot c' = l*8+j  ->  orig b1 index = head*64 + (j&3)*16 + (l&7)*2 + (j>>2)
        int forig = (j & 3) * 16 + (l & 7) * 2 + (j >> 2);
        float v = acc[j] * rden + b1[h * 64 + forig];
        v = v > 0.f ? v : (__expf(v) - 1.f);    // ELU
        o[j] = f2bf(v);
    }
    *(short8*)(hcat + (size_t)n * 512 + l * 8) = o;
}

// ---------------- gemm2: row-major hcat A-frags + fused s2 scores ----------------
__global__ __launch_bounds__(256) void gemm2(const short* __restrict__ hcat,
                                             const short* __restrict__ Wp2,
                                             const float* __restrict__ a2,
                                             short* __restrict__ h2,
                                             float* __restrict__ s2s,
                                             float* __restrict__ s2d) {
    int w = threadIdx.x >> 6, l = threadIdx.x & 63;
    int rt = blockIdx.x * 4 + w;                  // < N_RT_PAD
    int arow = rt * 16 + (l & 15);
    const short* aBase = hcat + (size_t)arow * 512 + (l >> 4) * 8;
    f32x4 acc[3];
#pragma unroll
    for (int ct = 0; ct < 3; ++ct) acc[ct] = (f32x4){0.f, 0.f, 0.f, 0.f};
#pragma unroll 2
    for (int ks = 0; ks < 16; ++ks) {
        short8 a = *(const short8*)(aBase + ks * 32);
        const short* bp = Wp2 + (size_t)(ks * 3) * 512 + l * 8;
#pragma unroll
        for (int ct = 0; ct < 3; ++ct) {
            short8 b = *(const short8*)(bp + ct * 512);
            acc[ct] = __builtin_amdgcn_mfma_f32_16x16x32_bf16(a, b, acc[ct], 0, 0, 0);
        }
    }
    float ps[4] = {0.f, 0.f, 0.f, 0.f}, pd[4] = {0.f, 0.f, 0.f, 0.f};
    int cl = l & 15, rb = (l >> 4) * 4;
#pragma unroll
    for (int ct = 0; ct < 3; ++ct) {
        int col = ct * 16 + cl;
        if (col < NCLASS) {
#pragma unroll
            for (int r = 0; r < 4; ++r) {
                ps[r] += acc[ct][r] * a2[col];
                pd[r] += acc[ct][r] * a2[NCLASS + col];
                int row = rt * 16 + rb + r;
                if (row < N_NODES) h2[(size_t)row * NCLASS + col] = f2bf(acc[ct][r]);
            }
        }
    }
#pragma unroll
    for (int mask = 1; mask < 16; mask <<= 1)
#pragma unroll
        for (int r = 0; r < 4; ++r) {
            ps[r] += __shfl_xor(ps[r], mask);
            pd[r] += __shfl_xor(pd[r], mask);
        }
    if (cl == 0) {
#pragma unroll
        for (int r = 0; r < 4; ++r) {
            int row = rt * 16 + rb + r;
            if (row < N_NODES) { s2s[row] = ps[r]; s2d[row] = pd[r]; }
        }
    }
}

// ---------------- fused layer-2 attention + log_softmax: pipelined 4-wide gather ----------------
__global__ __launch_bounds__(256, 4) void att2(const int* __restrict__ ptr,
                                               const int* __restrict__ esrc,
                                               const float* __restrict__ s2s,
                                               const float* __restrict__ s2d,
                                               const short* __restrict__ h2,
                                               const float* __restrict__ b2,
                                               float* __restrict__ out) {
    int n = blockIdx.x * 4 + (threadIdx.x >> 6);
    int l = threadIdx.x & 63;
    if (n >= N_NODES) return;
    int beg = ptr[n], end = ptr[n + 1];
    float sd = s2d[n];
    float den = 0.f, acc = 0.f;
    bool act = (l < NCLASS);
    if (beg < end) {
        int last = end - 1;
        int p1 = (beg + 1 <= last) ? beg + 1 : last;
        int p2 = (beg + 2 <= last) ? beg + 2 : last;
        int p3 = (beg + 3 <= last) ? beg + 3 : last;
        int s0 = esrc[beg], s1 = esrc[p1], s2 = esrc[p2], s3 = esrc[p3];
        float h0  = act ? bf2f(h2[(size_t)s0 * NCLASS + l]) : 0.f;
        float h1  = act ? bf2f(h2[(size_t)s1 * NCLASS + l]) : 0.f;
        float hh2 = act ? bf2f(h2[(size_t)s2 * NCLASS + l]) : 0.f;
        float h3  = act ? bf2f(h2[(size_t)s3 * NCLASS + l]) : 0.f;
        float ss0 = s2s[s0], ss1 = s2s[s1], ss2 = s2s[s2], ss3 = s2s[s3];
        for (int i = beg; i < end; i += 4) {
            int ni = i + 4;
            float u0 = h0, u1 = h1, u2 = hh2, u3 = h3;
            float ts0 = ss0, ts1 = ss1, ts2 = ss2, ts3 = ss3;
            if (ni < end) {                       // wave-uniform prefetch of next group
                int q1 = (ni + 1 <= last) ? ni + 1 : last;
                int q2 = (ni + 2 <= last) ? ni + 2 : last;
                int q3 = (ni + 3 <= last) ? ni + 3 : last;
                int t0 = esrc[ni], t1 = esrc[q1], t2 = esrc[q2], t3 = esrc[q3];
                u0  = act ? bf2f(h2[(size_t)t0 * NCLASS + l]) : 0.f;
                u1  = act ? bf2f(h2[(size_t)t1 * NCLASS + l]) : 0.f;
                u2  = act ? bf2f(h2[(size_t)t2 * NCLASS + l]) : 0.f;
                u3  = act ? bf2f(h2[(size_t)t3 * NCLASS + l]) : 0.f;
                ts0 = s2s[t0]; ts1 = s2s[t1]; ts2 = s2s[t2]; ts3 = s2s[t3];
            }
            float e0 = ss0 + sd, e1 = ss1 + sd, e2 = ss2 + sd, e3 = ss3 + sd;
            e0 = fmaxf(e0, NEG_SLOPE * e0);
            e1 = fmaxf(e1, NEG_SLOPE * e1);
            e2 = fmaxf(e2, NEG_SLOPE * e2);
            e3 = fmaxf(e3, NEG_SLOPE * e3);
            float w0 = __expf(e0);
            float w1 = (i + 1 < end) ? __expf(e1) : 0.f;
            float w2 = (i + 2 < end) ? __expf(e2) : 0.f;
            float w3 = (i + 3 < end) ? __expf(e3) : 0.f;
            den += (w0 + w1) + (w2 + w3);
            acc += (w0 * h0 + w1 * h1) + (w2 * hh2 + w3 * h3);
            h0 = u0; h1 = u1; hh2 = u2; h3 = u3;
            ss0 = ts0; ss1 = ts1; ss2 = ts2; ss3 = ts3;
        }
    }
    float v = act ? acc / fmaxf(den, 1e-16f) + b2[l] : -INFINITY;
    float mx = v;
#pragma unroll
    for (int o = 32; o; o >>= 1) mx = fmaxf(mx, __shfl_down(mx, o));
    mx = __shfl(mx, 0);
    float ex = act ? __expf(v - mx) : 0.f;
    float s = ex;
#pragma unroll
    for (int o = 32; o; o >>= 1) s += __shfl_down(s, o);
    s = __shfl(s, 0);
    float ls = __logf(s);
    if (act) out[(size_t)n * NCLASS + l] = v - mx - ls;
}

// ---------------- launch ----------------

extern "C" void kernel_launch(void* const* d_in, const int* in_sizes, int n_in,
                              void* d_out, int out_size, void* d_ws, size_t ws_size,
                              hipStream_t stream) {
    const float* x  = (const float*)d_in[0];
    const int*   el = (const int*)d_in[1];
    const float* W1 = (const float*)d_in[2];
    const float* a1 = (const float*)d_in[3];
    const float* b1 = (const float*)d_in[4];
    const float* W2 = (const float*)d_in[5];
    const float* a2 = (const float*)d_in[6];
    const float* b2 = (const float*)d_in[7];
    float* out = (float*)d_out;

    short* sbase = (short*)d_ws;
    short* Wp1a  = sbase;                          //    294,912 (in formerly-unused region)
    short* hcat  = sbase + 25624576;               // 25,624,576 (row-major, permuted cols)
    short* h1p   = sbase + 51249152;               // 25,600,000
    short* Wp2   = sbase + 77111296;               //     24,576
    short* h2    = sbase + 77135872;               //  2,000,000
    float* fbase = (float*)(sbase + 79135872);
    float* s1s   = fbase;                          //    400,000
    float* s1d   = fbase + 400000;                 //    400,000
    float* s2s   = fbase + 800000;                 //     50,000
    float* s2d   = fbase + 850000;                 //     50,000
    int*   ibase = (int*)(fbase + 900000);
    int*   deg    = ibase;                         //     50,000
    int*   ptr    = ibase + 50000;                 //     50,001
    int*   cursor = ibase + 100001;                //     50,000
    int*   esrc   = ibase + 150001;                //    800,000
    int*   loc    = ibase + 950001;                //     50,000
    int*   bsum   = ibase + 1000001;               //         64

    // ---- CSR build ----
    hipMemsetAsync(deg, 0, (size_t)N_NODES * 4, stream);
    count_deg<<<(N_EDGES + 255) / 256, 256, 0, stream>>>(el, deg);
    scan1<<<SCAN_NBLK, 256, 0, stream>>>(deg, loc, bsum);
    scan3<<<SCAN_NBLK, 256, 0, stream>>>(deg, loc, bsum, ptr, cursor);
    scatter_k<<<(N_EDGES + 255) / 256, 256, 0, stream>>>(el, cursor, esrc);

    // ---- weight packing (Wa score columns folded into Wp1a) ----
    pack_w<<<156, 256, 0, stream>>>(W1, W2, a1, Wp1a, Wp2);

    // ---- layer 1 ----
    gemm1<<<N_RT_PAD / RT_BLK, 256, 0, stream>>>(x, Wp1a, h1p, s1s, s1d);
    att1<<<ATT1_CHUNK / 4, 256, 0, stream>>>(ptr, esrc, s1s, s1d, h1p, b1, hcat, 0);
    att1<<<ATT1_CHUNK / 4, 256, 0, stream>>>(ptr, esrc, s1s, s1d, h1p, b1, hcat, 25000);

    // ---- layer 2 ----
    gemm2<<<N_RT_PAD / 4, 256, 0, stream>>>(hcat, Wp2, a2, h2, s2s, s2d);
    att2<<<(N_NODES + 3) / 4, 256, 0, stream>>>(ptr, esrc, s2s, s2d, h2, b2, out);
}

// Round 12
// 497.871 us; speedup vs baseline: 1.0530x; 1.0345x over previous
//
// GAT fused pipeline v3.3 — att2 restructured: 4 edge-groups x 16 lanes (4 independent
// load chains, h2 padded to 64 cols, short4v gathers, group-split exp). att1 4-way
// split for residual-kernel visibility. gemm1 v3 frozen.
#include <hip/hip_runtime.h>
#include <math.h>

#define N_NODES 50000
#define N_EDGES 800000
#define NFEAT 512
#define NHID 64
#define NHEAD 8
#define NCLASS 40
#define NEG_SLOPE 0.2f

#define N_RT 3125           // 50000/16 row tiles
#define N_RT_PAD 3128       // padded to multiple of 8
#define SCAN_NBLK 49        // ceil(50000/1024)
#define RT_BLK 4            // rowtiles per gemm1 block (64 rows)
#define ATT1_CHUNK 12500    // nodes per att1 dispatch (4 dispatches)

typedef __attribute__((ext_vector_type(8))) short short8;
typedef __attribute__((ext_vector_type(4))) short short4v;
typedef __attribute__((ext_vector_type(4))) float f32x4;

__device__ __forceinline__ float bf2f(short s) {
    return __uint_as_float(((unsigned)(unsigned short)s) << 16);
}
__device__ __forceinline__ short f2bf(float f) {
    unsigned u = __float_as_uint(f);
    unsigned r = (u + 0x7FFFu + ((u >> 16) & 1u)) >> 16;
    return (short)(unsigned short)r;
}
// LDS 16B-slot swizzle: staging writes 32-way -> conflict-free (verified r7:
// SQ_LDS_BANK_CONFLICT 2.8M -> 0); reads stay conflict-free; bijective.
__device__ __forceinline__ int swz(int s) { return s ^ ((s >> 4) & 7); }

// h1 row permutation: slot c' = head*64 + f'; orig feature: forig = ((f'&3)<<4)|(f'>>2).
// Wp1a layout (augmented): ((g*16+ks)*9 + ct)*64*8 shorts; ct=8 holds score
// columns [ss_h(2g), sd_h(2g), ss_h(2g+1), sd_h(2g+1), 0...] built from Wa = W1@a1.

// ---------------- CSR build ----------------

__global__ void count_deg(const int* __restrict__ el, int* __restrict__ deg) {
    int e = blockIdx.x * blockDim.x + threadIdx.x;
    if (e < N_EDGES) atomicAdd(&deg[el[N_EDGES + e]], 1);
}

__global__ __launch_bounds__(256) void scan1(const int* __restrict__ deg,
                                             int* __restrict__ loc,
                                             int* __restrict__ bsum) {
    int tid = threadIdx.x, lane = tid & 63, w = tid >> 6;
    int base = blockIdx.x * 1024 + tid * 4;
    int d0 = (base + 0 < N_NODES) ? deg[base + 0] : 0;
    int d1 = (base + 1 < N_NODES) ? deg[base + 1] : 0;
    int d2 = (base + 2 < N_NODES) ? deg[base + 2] : 0;
    int d3 = (base + 3 < N_NODES) ? deg[base + 3] : 0;
    int s0 = d0, s1 = s0 + d1, s2 = s1 + d2, s3 = s2 + d3;
    int t = s3;
#pragma unroll
    for (int d = 1; d < 64; d <<= 1) {
        int u = __shfl_up(t, d);
        if (lane >= d) t += u;
    }
    __shared__ int wsum[4];
    if (lane == 63) wsum[w] = t;
    __syncthreads();
    int woff = 0;
#pragma unroll
    for (int j = 0; j < 4; ++j) woff += (j < w) ? wsum[j] : 0;
    int excl = woff + t - s3;
    if (base + 0 < N_NODES) loc[base + 0] = excl + s0;
    if (base + 1 < N_NODES) loc[base + 1] = excl + s1;
    if (base + 2 < N_NODES) loc[base + 2] = excl + s2;
    if (base + 3 < N_NODES) loc[base + 3] = excl + s3;
    if (tid == 255) bsum[blockIdx.x] = woff + t;
}

// scan3 with scan2 folded in: each block reduces bsum[0..bid) itself
__global__ __launch_bounds__(256) void scan3(const int* __restrict__ deg,
                                             const int* __restrict__ loc,
                                             const int* __restrict__ bsum,
                                             int* __restrict__ ptr,
                                             int* __restrict__ cursor) {
    __shared__ int sOff;
    if (threadIdx.x < 64) {
        int lane = threadIdx.x;
        int v = (lane < SCAN_NBLK && lane < (int)blockIdx.x) ? bsum[lane] : 0;
#pragma unroll
        for (int m = 1; m < 64; m <<= 1) v += __shfl_xor(v, m);
        if (lane == 0) sOff = v;
    }
    __syncthreads();
    int off = sOff;
    int base = blockIdx.x * 1024 + threadIdx.x * 4;
    if (blockIdx.x == 0 && threadIdx.x == 0) ptr[0] = 0;
#pragma unroll
    for (int k = 0; k < 4; ++k) {
        int i = base + k;
        if (i < N_NODES) {
            int P = off + loc[i];
            ptr[i + 1] = P;
            cursor[i] = P - deg[i];
        }
    }
}

__global__ void scatter_k(const int* __restrict__ el, int* __restrict__ cursor,
                          int* __restrict__ esrc) {
    int e = blockIdx.x * blockDim.x + threadIdx.x;
    if (e >= N_EDGES) return;
    int dst = el[N_EDGES + e];
    int p = atomicAdd(&cursor[dst], 1);
    esrc[p] = el[e];
}

// ---------------- pack W1(+scores), W2 into MFMA B-fragment layout (bf16) ----------------
__global__ __launch_bounds__(256) void pack_w(const float* __restrict__ W1,
                                              const float* __restrict__ W2,
                                              const float* __restrict__ a1,
                                              short* __restrict__ Wp1a,
                                              short* __restrict__ Wp2) {
    int t = blockIdx.x * 256 + threadIdx.x;
    if (t < 36864) {                    // 4g x 16ks x 9ct x 64l
        int l = t & 63;
        int idx = t >> 6;               // 0..575
        int ct = idx % 9;
        int ksg = idx / 9;              // g*16+ks
        int ks = ksg & 15, g = ksg >> 4;
        short8 o;
        if (ct < 8) {
            int c = g * 128 + ct * 16 + (l & 15);
            int head = c >> 6, f = c & 63;
            int k0 = ks * 32 + (l >> 4) * 8;
#pragma unroll
            for (int j = 0; j < 8; ++j)
                o[j] = f2bf(W1[(size_t)head * NFEAT * NHID + (k0 + j) * NHID + f]);
        } else {
            // score columns: col 0..3 = [ss(2g), sd(2g), ss(2g+1), sd(2g+1)]
            int col = l & 15;
            int k0 = ks * 32 + (l >> 4) * 8;
#pragma unroll
            for (int j = 0; j < 8; ++j) o[j] = 0;
            if (col < 4) {
                int head = 2 * g + (col >> 1);
                const float* av = a1 + head * 128 + (col & 1) * 64;
                const float* wb = W1 + (size_t)head * NFEAT * NHID;
#pragma unroll
                for (int j = 0; j < 8; ++j) {
                    const float* wr = wb + (size_t)(k0 + j) * NHID;
                    float s = 0.f;
                    for (int f = 0; f < NHID; ++f) s += wr[f] * av[f];
                    o[j] = f2bf(s);
                }
            }
        }
        *(short8*)(Wp1a + (size_t)t * 8) = o;
    } else if (t < 36864 + 3072) {
        int u = t - 36864;
        int l = u & 63;
        int kc = u >> 6;                 // ks*3+ct
        int ct2 = kc % 3, ks = kc / 3;
        int col = ct2 * 16 + (l & 15);
        short8 o;
#pragma unroll
        for (int j = 0; j < 8; ++j) {
            int kp = ks * 32 + (l >> 4) * 8 + j;      // permuted K slot (= c')
            int head = kp >> 6, fp = kp & 63;
            int l15 = fp >> 2, ctp = fp & 3;
            int ct = ((head & 1) << 2) | ctp;
            int gg = head >> 1;
            int orig_k = gg * 128 + ct * 16 + l15;
            o[j] = (col < NCLASS) ? f2bf(W2[(size_t)orig_k * NCLASS + col]) : (short)0;
        }
        *(short8*)(Wp2 + (size_t)u * 8) = o;
    }
}

// ---------------- gemm1 v3: 4 rowtiles/block, scores as 9th B-tile, no shfl epilogue ----
__global__ __launch_bounds__(256, 2) void gemm1(const float* __restrict__ x,
                                                const short* __restrict__ Wp1a,
                                                short* __restrict__ h1p,
                                                float* __restrict__ s1s,
                                                float* __restrict__ s1d) {
    __shared__ short As[RT_BLK * 16 * 64 * 8];     // 64 KB
    int w = threadIdx.x >> 6, l = threadIdx.x & 63;
    int g = w;                                 // wave = colgroup
    int rt0 = blockIdx.x * RT_BLK;
    int row0 = rt0 * 16;

    // stage 64 rows x 512 cols of x into LDS A-frag layout (swizzled slots)
#pragma unroll
    for (int u = 0; u < 4 * RT_BLK; ++u) {
        int idx = threadIdx.x + u * 256;       // 0..4095
        int rl = idx >> 6, cg = idx & 63;      // row-local (0..63), col-group
        int row = row0 + rl;
        short8 o;
        if (row < N_NODES) {
            const float* p = x + (size_t)row * NFEAT + cg * 8;
            f32x4 v0 = __builtin_nontemporal_load((const f32x4*)p);
            f32x4 v1 = __builtin_nontemporal_load((const f32x4*)(p + 4));
            o[0] = f2bf(v0[0]); o[1] = f2bf(v0[1]); o[2] = f2bf(v0[2]); o[3] = f2bf(v0[3]);
            o[4] = f2bf(v1[0]); o[5] = f2bf(v1[1]); o[6] = f2bf(v1[2]); o[7] = f2bf(v1[3]);
        } else {
#pragma unroll
            for (int j = 0; j < 8; ++j) o[j] = 0;
        }
        int rtl = rl >> 4, rloc = rl & 15, ks = cg >> 2, sub = cg & 3;
        int slot = (rtl * 16 + ks) * 64 + rloc + sub * 16;
        *(short8*)(As + swz(slot) * 8) = o;
    }
    __syncthreads();

    f32x4 acc[RT_BLK][9];
#pragma unroll
    for (int i = 0; i < RT_BLK; ++i)
#pragma unroll
        for (int ct = 0; ct < 9; ++ct) acc[i][ct] = (f32x4){0.f, 0.f, 0.f, 0.f};

    const short* bP = Wp1a + (size_t)g * (16 * 9 * 512) + l * 8;   // ks stride 4608
#pragma unroll 2
    for (int ks = 0; ks < 16; ++ks) {
        short8 b[9];
#pragma unroll
        for (int ct = 0; ct < 9; ++ct) b[ct] = *(const short8*)(bP + ks * 4608 + ct * 512);
        short8 a[RT_BLK];
#pragma unroll
        for (int i = 0; i < RT_BLK; ++i)
            a[i] = *(const short8*)(As + swz((i * 16 + ks) * 64 + l) * 8);
#pragma unroll
        for (int i = 0; i < RT_BLK; ++i)
#pragma unroll
            for (int ct = 0; ct < 9; ++ct)
                acc[i][ct] = __builtin_amdgcn_mfma_f32_16x16x32_bf16(a[i], b[ct], acc[i][ct], 0, 0, 0);
    }

    int l15 = l & 15;
    int rbase = (l >> 4) * 4;
#pragma unroll
    for (int i = 0; i < RT_BLK; ++i)
#pragma unroll
        for (int r = 0; r < 4; ++r) {
            int row = (rt0 + i) * 16 + rbase + r;
            if (row < N_NODES) {
                short4v o0, o1;
#pragma unroll
                for (int c = 0; c < 4; ++c) { o0[c] = f2bf(acc[i][c][r]); o1[c] = f2bf(acc[i][4 + c][r]); }
                size_t base = (size_t)row * 512 + g * 128 + l15 * 4;
                *(short4v*)(h1p + base) = o0;
                *(short4v*)(h1p + base + 64) = o1;
                float sv = acc[i][8][r];
                if (l15 == 0)      s1s[row * 8 + 2 * g]     = sv;
                else if (l15 == 1) s1d[row * 8 + 2 * g]     = sv;
                else if (l15 == 2) s1s[row * 8 + 2 * g + 1] = sv;
                else if (l15 == 3) s1d[row * 8 + 2 * g + 1] = sv;
            }
        }
}

// ---------------- fused layer-1 attention: wave per dst, ALL heads ----------------
// Node-range chunked (4 dispatches) for profiler visibility; pipelined 4-wide gather.
__global__ __launch_bounds__(256, 4) void att1(const int* __restrict__ ptr,
                                               const int* __restrict__ esrc,
                                               const float* __restrict__ s1s,
                                               const float* __restrict__ s1d,
                                               const short* __restrict__ h1p,
                                               const float* __restrict__ b1,
                                               short* __restrict__ hcat,
                                               int n0) {
    int n = n0 + blockIdx.x * 4 + (threadIdx.x >> 6);
    int l = threadIdx.x & 63;
    if (n >= N_NODES) return;
    int beg = ptr[n], end = ptr[n + 1];
    int h = l >> 3;
    float sd = s1d[n * 8 + h];
    float den = 0.f;
    float acc[8] = {0.f, 0.f, 0.f, 0.f, 0.f, 0.f, 0.f, 0.f};
    const short* hb = h1p + l * 8;
    if (beg < end) {
        int last = end - 1;
        int p1 = (beg + 1 <= last) ? beg + 1 : last;
        int p2 = (beg + 2 <= last) ? beg + 2 : last;
        int p3 = (beg + 3 <= last) ? beg + 3 : last;
        int s0 = esrc[beg], s1 = esrc[p1], s2 = esrc[p2], s3 = esrc[p3];
        short8 v0 = *(const short8*)(hb + (size_t)s0 * 512);
        short8 v1 = *(const short8*)(hb + (size_t)s1 * 512);
        short8 v2 = *(const short8*)(hb + (size_t)s2 * 512);
        short8 v3 = *(const short8*)(hb + (size_t)s3 * 512);
        float ss0 = s1s[s0 * 8 + h], ss1 = s1s[s1 * 8 + h];
        float ss2 = s1s[s2 * 8 + h], ss3 = s1s[s3 * 8 + h];
        for (int i = beg; i < end; i += 4) {
            int ni = i + 4;
            int t0 = s0, t1 = s1, t2 = s2, t3 = s3;
            short8 u0 = v0, u1 = v1, u2 = v2, u3 = v3;
            float ts0 = ss0, ts1 = ss1, ts2 = ss2, ts3 = ss3;
            if (ni < end) {                       // wave-uniform branch
                int q1 = (ni + 1 <= last) ? ni + 1 : last;
                int q2 = (ni + 2 <= last) ? ni + 2 : last;
                int q3 = (ni + 3 <= last) ? ni + 3 : last;
                t0 = esrc[ni]; t1 = esrc[q1]; t2 = esrc[q2]; t3 = esrc[q3];
                u0 = *(const short8*)(hb + (size_t)t0 * 512);
                u1 = *(const short8*)(hb + (size_t)t1 * 512);
                u2 = *(const short8*)(hb + (size_t)t2 * 512);
                u3 = *(const short8*)(hb + (size_t)t3 * 512);
                ts0 = s1s[t0 * 8 + h]; ts1 = s1s[t1 * 8 + h];
                ts2 = s1s[t2 * 8 + h]; ts3 = s1s[t3 * 8 + h];
            }
            float e0 = ss0 + sd, e1 = ss1 + sd, e2 = ss2 + sd, e3 = ss3 + sd;
            e0 = fmaxf(e0, NEG_SLOPE * e0);
            e1 = fmaxf(e1, NEG_SLOPE * e1);
            e2 = fmaxf(e2, NEG_SLOPE * e2);
            e3 = fmaxf(e3, NEG_SLOPE * e3);
            float w0 = __expf(e0);
            float w1 = (i + 1 < end) ? __expf(e1) : 0.f;
            float w2 = (i + 2 < end) ? __expf(e2) : 0.f;
            float w3 = (i + 3 < end) ? __expf(e3) : 0.f;
            den += (w0 + w1) + (w2 + w3);
#pragma unroll
            for (int j = 0; j < 8; ++j)
                acc[j] += (w0 * bf2f(v0[j]) + w1 * bf2f(v1[j])) +
                          (w2 * bf2f(v2[j]) + w3 * bf2f(v3[j]));
            s0 = t0; s1 = t1; s2 = t2; s3 = t3;
            v0 = u0; v1 = u1; v2 = u2; v3 = u3;
            ss0 = ts0; ss1 = ts1; ss2 = ts2; ss3 = ts3;
        }
    }
    float rden = 1.f / fmaxf(den, 1e-16f);
    short8 o;
#pragma unroll
    for (int j = 0; j < 8; ++j) {
        // permuted slot c' = l*8+j  ->  orig b1 index = head*64 + (j&3)*16 + (l&7)*2 + (j>>2)
        int forig = (j & 3) * 16 + (l & 7) * 2 + (j >> 2);
        float v = acc[j] * rden + b1[h * 64 + forig];
        v = v > 0.f ? v : (__expf(v) - 1.f);    // ELU
        o[j] = f2bf(v);
    }
    *(short8*)(hcat + (size_t)n * 512 + l * 8) = o;
}

// ---------------- gemm2: row-major hcat A-frags + fused s2 scores; h2 PADDED to 64 cols ----
__global__ __launch_bounds__(256) void gemm2(const short* __restrict__ hcat,
                                             const short* __restrict__ Wp2,
                                             const float* __restrict__ a2,
                                             short* __restrict__ h2p,
                                             float* __restrict__ s2s,
                                             float* __restrict__ s2d) {
    int w = threadIdx.x >> 6, l = threadIdx.x & 63;
    int rt = blockIdx.x * 4 + w;                  // < N_RT_PAD
    int arow = rt * 16 + (l & 15);
    const short* aBase = hcat + (size_t)arow * 512 + (l >> 4) * 8;
    f32x4 acc[3];
#pragma unroll
    for (int ct = 0; ct < 3; ++ct) acc[ct] = (f32x4){0.f, 0.f, 0.f, 0.f};
#pragma unroll 2
    for (int ks = 0; ks < 16; ++ks) {
        short8 a = *(const short8*)(aBase + ks * 32);
        const short* bp = Wp2 + (size_t)(ks * 3) * 512 + l * 8;
#pragma unroll
        for (int ct = 0; ct < 3; ++ct) {
            short8 b = *(const short8*)(bp + ct * 512);
            acc[ct] = __builtin_amdgcn_mfma_f32_16x16x32_bf16(a, b, acc[ct], 0, 0, 0);
        }
    }
    float ps[4] = {0.f, 0.f, 0.f, 0.f}, pd[4] = {0.f, 0.f, 0.f, 0.f};
    int cl = l & 15, rb = (l >> 4) * 4;
#pragma unroll
    for (int ct = 0; ct < 3; ++ct) {
        int col = ct * 16 + cl;
#pragma unroll
        for (int r = 0; r < 4; ++r) {
            int row = rt * 16 + rb + r;
            if (row < N_NODES) h2p[(size_t)row * 64 + col] = f2bf(acc[ct][r]);
        }
        if (col < NCLASS) {
#pragma unroll
            for (int r = 0; r < 4; ++r) {
                ps[r] += acc[ct][r] * a2[col];
                pd[r] += acc[ct][r] * a2[NCLASS + col];
            }
        }
    }
#pragma unroll
    for (int mask = 1; mask < 16; mask <<= 1)
#pragma unroll
        for (int r = 0; r < 4; ++r) {
            ps[r] += __shfl_xor(ps[r], mask);
            pd[r] += __shfl_xor(pd[r], mask);
        }
    if (cl == 0) {
#pragma unroll
        for (int r = 0; r < 4; ++r) {
            int row = rt * 16 + rb + r;
            if (row < N_NODES) { s2s[row] = ps[r]; s2d[row] = pd[r]; }
        }
    }
}

// ---------------- fused layer-2 attention + log_softmax: 4 edge-groups x 16 lanes ----
// grp = l>>4 owns edge i+grp (4 independent load chains); cl = l&15 owns classes
// cl*4..cl*4+3 (short4v from h2p padded to 64). Group-reduce via shfl_xor(16,32).
__global__ __launch_bounds__(256, 4) void att2(const int* __restrict__ ptr,
                                               const int* __restrict__ esrc,
                                               const float* __restrict__ s2s,
                                               const float* __restrict__ s2d,
                                               const short* __restrict__ h2p,
                                               const float* __restrict__ b2,
                                               float* __restrict__ out) {
    int n = blockIdx.x * 4 + (threadIdx.x >> 6);
    int l = threadIdx.x & 63;
    if (n >= N_NODES) return;
    int beg = ptr[n], end = ptr[n + 1];
    float sd = s2d[n];
    int grp = l >> 4, cl = l & 15;
    bool act16 = cl < 10;                 // classes cl*4..cl*4+3 valid iff cl<10
    float den = 0.f, a0 = 0.f, a1 = 0.f, a2v = 0.f, a3 = 0.f;
    if (beg < end) {
        int last = end - 1;
        for (int i = beg; i < end; i += 4) {
            int e = i + grp;
            bool valid = e < end;
            int src = esrc[valid ? e : last];
            float sc = s2s[src] + sd;
            sc = fmaxf(sc, NEG_SLOPE * sc);
            float wgt = valid ? __expf(sc) : 0.f;
            short4v hv = *(const short4v*)(h2p + (size_t)src * 64 + cl * 4);
            den += wgt;
            if (act16) {
                a0 += wgt * bf2f(hv[0]);
                a1 += wgt * bf2f(hv[1]);
                a2v += wgt * bf2f(hv[2]);
                a3 += wgt * bf2f(hv[3]);
            }
        }
    }
    // sum the 4 edge-groups (lanes with equal cl): xor 16, 32
#pragma unroll
    for (int m = 16; m < 64; m <<= 1) {
        den += __shfl_xor(den, m);
        a0  += __shfl_xor(a0, m);
        a1  += __shfl_xor(a1, m);
        a2v += __shfl_xor(a2v, m);
        a3  += __shfl_xor(a3, m);
    }
    float rden = 1.f / fmaxf(den, 1e-16f);
    float v0, v1, v2, v3;
    if (act16) {
        int c0 = cl * 4;
        v0 = a0 * rden + b2[c0 + 0];
        v1 = a1 * rden + b2[c0 + 1];
        v2 = a2v * rden + b2[c0 + 2];
        v3 = a3 * rden + b2[c0 + 3];
    } else { v0 = v1 = v2 = v3 = -INFINITY; }
    // log_softmax over 40 classes: reduce within each 16-lane quarter (quarters identical)
    float mx = fmaxf(fmaxf(v0, v1), fmaxf(v2, v3));
#pragma unroll
    for (int m = 1; m < 16; m <<= 1) mx = fmaxf(mx, __shfl_xor(mx, m));
    float e0 = act16 ? __expf(v0 - mx) : 0.f;
    float e1 = act16 ? __expf(v1 - mx) : 0.f;
    float e2 = act16 ? __expf(v2 - mx) : 0.f;
    float e3 = act16 ? __expf(v3 - mx) : 0.f;
    float s = (e0 + e1) + (e2 + e3);
#pragma unroll
    for (int m = 1; m < 16; m <<= 1) s += __shfl_xor(s, m);
    float ls = __logf(s);
    if (l < 16 && act16) {
        int c0 = cl * 4;
        out[(size_t)n * NCLASS + c0 + 0] = v0 - mx - ls;
        out[(size_t)n * NCLASS + c0 + 1] = v1 - mx - ls;
        out[(size_t)n * NCLASS + c0 + 2] = v2 - mx - ls;
        out[(size_t)n * NCLASS + c0 + 3] = v3 - mx - ls;
    }
}

// ---------------- launch ----------------

extern "C" void kernel_launch(void* const* d_in, const int* in_sizes, int n_in,
                              void* d_out, int out_size, void* d_ws, size_t ws_size,
                              hipStream_t stream) {
    const float* x  = (const float*)d_in[0];
    const int*   el = (const int*)d_in[1];
    const float* W1 = (const float*)d_in[2];
    const float* a1 = (const float*)d_in[3];
    const float* b1 = (const float*)d_in[4];
    const float* W2 = (const float*)d_in[5];
    const float* a2 = (const float*)d_in[6];
    const float* b2 = (const float*)d_in[7];
    float* out = (float*)d_out;

    short* sbase = (short*)d_ws;
    short* Wp1a  = sbase;                          //    294,912
    short* h2p   = sbase + 4000000;                //  3,200,000 (padded h2: 50000 x 64)
    short* hcat  = sbase + 25624576;               // 25,624,576 (row-major, permuted cols)
    short* h1p   = sbase + 51249152;               // 25,600,000
    short* Wp2   = sbase + 77111296;               //     24,576
    float* fbase = (float*)(sbase + 79135872);
    float* s1s   = fbase;                          //    400,000
    float* s1d   = fbase + 400000;                 //    400,000
    float* s2s   = fbase + 800000;                 //     50,000
    float* s2d   = fbase + 850000;                 //     50,000
    int*   ibase = (int*)(fbase + 900000);
    int*   deg    = ibase;                         //     50,000
    int*   ptr    = ibase + 50000;                 //     50,001
    int*   cursor = ibase + 100001;                //     50,000
    int*   esrc   = ibase + 150001;                //    800,000
    int*   loc    = ibase + 950001;                //     50,000
    int*   bsum   = ibase + 1000001;               //         64

    // ---- CSR build ----
    hipMemsetAsync(deg, 0, (size_t)N_NODES * 4, stream);
    count_deg<<<(N_EDGES + 255) / 256, 256, 0, stream>>>(el, deg);
    scan1<<<SCAN_NBLK, 256, 0, stream>>>(deg, loc, bsum);
    scan3<<<SCAN_NBLK, 256, 0, stream>>>(deg, loc, bsum, ptr, cursor);
    scatter_k<<<(N_EDGES + 255) / 256, 256, 0, stream>>>(el, cursor, esrc);

    // ---- weight packing (Wa score columns folded into Wp1a) ----
    pack_w<<<156, 256, 0, stream>>>(W1, W2, a1, Wp1a, Wp2);

    // ---- layer 1 ----
    gemm1<<<N_RT_PAD / RT_BLK, 256, 0, stream>>>(x, Wp1a, h1p, s1s, s1d);
    att1<<<ATT1_CHUNK / 4, 256, 0, stream>>>(ptr, esrc, s1s, s1d, h1p, b1, hcat, 0);
    att1<<<ATT1_CHUNK / 4, 256, 0, stream>>>(ptr, esrc, s1s, s1d, h1p, b1, hcat, 12500);
    att1<<<ATT1_CHUNK / 4, 256, 0, stream>>>(ptr, esrc, s1s, s1d, h1p, b1, hcat, 25000);
    att1<<<ATT1_CHUNK / 4, 256, 0, stream>>>(ptr, esrc, s1s, s1d, h1p, b1, hcat, 37500);

    // ---- layer 2 ----
    gemm2<<<N_RT_PAD / 4, 256, 0, stream>>>(hcat, Wp2, a2, h2p, s2s, s2d);
    att2<<<(N_NODES + 3) / 4, 256, 0, stream>>>(ptr, esrc, s2s, s2d, h2p, b2, out);
}